// Round 16
// baseline (127.724 us; speedup 1.0000x reference)
//
#include <hip/hip_runtime.h>

#define N_NODES 50000
#define N_EDGES 800000
#define F 128
#define ROWB 384   // uxt row: [0,128)=u fp8, [128,384)=xt bf16

typedef unsigned short u16;
typedef __bf16 bf16x8 __attribute__((ext_vector_type(8)));
typedef float f32x4 __attribute__((ext_vector_type(4)));
typedef float f32x2 __attribute__((ext_vector_type(2)));

__device__ inline u16 f2bf(float f) {
  union { float f; unsigned u; } v; v.f = f;
  unsigned r = v.u + 0x7fffu + ((v.u >> 16) & 1u);
  return (u16)(r >> 16);
}

__device__ inline int clampi(int v) {
  v = v < 0 ? 0 : v;
  return v >= N_NODES ? N_NODES - 1 : v;
}

// fp8 e4m3 cvt via HW instruction (builtin if present, else inline asm)
__device__ inline f32x2 fp8x2_to_f32(unsigned w) {
#if __has_builtin(__builtin_amdgcn_cvt_pk_f32_fp8)
  return __builtin_amdgcn_cvt_pk_f32_fp8((int)w, false);
#else
  f32x2 r;
  asm("v_cvt_pk_f32_fp8 %0, %1" : "=v"(r) : "v"(w));
  return r;
#endif
}
__device__ inline unsigned f32_to_fp8(float a) {
#if __has_builtin(__builtin_amdgcn_cvt_pk_fp8_f32)
  return (unsigned)__builtin_amdgcn_cvt_pk_fp8_f32(a, a, 0, false) & 0xffu;
#else
  unsigned r;
  asm("v_cvt_pk_fp8_f32 %0, %1, %2" : "=v"(r) : "v"(a), "v"(a));
  return r & 0xffu;
#endif
}

// load 8 contiguous fp32 -> bf16x8 fragment
__device__ inline bf16x8 pack8(const float* __restrict__ p) {
  float4 a = *(const float4*)p;
  float4 b = *(const float4*)(p + 4);
  bf16x8 r;
  r[0] = (__bf16)a.x; r[1] = (__bf16)a.y; r[2] = (__bf16)a.z; r[3] = (__bf16)a.w;
  r[4] = (__bf16)b.x; r[5] = (__bf16)b.y; r[6] = (__bf16)b.z; r[7] = (__bf16)b.w;
  return r;
}

// ---------- pre: zero deg | transpose weights (disjoint block ranges) ----------
#define ZERO_BLOCKS 196
#define PREP_BLOCKS 192
__global__ __launch_bounds__(256) void pre_kernel(
    int* __restrict__ deg,
    const float* __restrict__ W, const float* __restrict__ W1,
    u16* __restrict__ wt, u16* __restrict__ w1t2)
{
  int bid = blockIdx.x;
  if (bid < ZERO_BLOCKS) {
    int i = bid * 256 + threadIdx.x;
    if (i < N_NODES) deg[i] = 0;
  } else {
    int t = (bid - ZERO_BLOCKS) * 256 + threadIdx.x;  // 0 .. 49151
    if (t < 128 * 128) {
      int k = t >> 7, n = t & 127;
      wt[n * 128 + k] = f2bf(W[k * 128 + n]);
    } else {
      int t2 = t - 128 * 128;           // 0 .. 32767
      int n2 = t2 >> 7, k = t2 & 127;   // n2: 0..255
      float v = (n2 < 128) ? W1[k * 128 + n2] : W1[(128 + k) * 128 + (n2 - 128)];
      w1t2[n2 * 128 + k] = f2bf(v);
    }
  }
}

// ---------- heavy: hist+loc (blocks [0,HIST)) | node GEMMs (blocks [HIST,..)) ----------
// GEMM phases run as two nf-halves (acc[4] not acc[8]) so the live set fits the
// allocator's ~52-VGPR budget without spilling (r15: acc[8] -> 24MB scratch traffic).
#define HIST_BLOCKS 832
#define GEMM_BLOCKS 782   // ceil(50000/64)
__global__ __launch_bounds__(256) void heavy_kernel(
    const int* __restrict__ ei, int* __restrict__ deg, int* __restrict__ loc,
    const float* __restrict__ x, const u16* __restrict__ wt,
    const u16* __restrict__ w1t2, const float* __restrict__ bias,
    const float* __restrict__ b1,
    unsigned char* __restrict__ uxt, u16* __restrict__ vout)
{
  __shared__ u16 wl[128 * 128];  // 32KB, slot XOR-swizzled by (row&7)
  int bid = blockIdx.x;
  if (bid < HIST_BLOCKS) {
    // ----- histogram + per-edge rank; latency hides under GEMM blocks -----
    int stride = HIST_BLOCKS * 256;
    for (int e = bid * 256 + threadIdx.x; e < N_EDGES; e += stride)
      loc[e] = atomicAdd(&deg[clampi(ei[N_EDGES + e])], 1);
    return;
  }
  // ----- node GEMMs: xt(bf16), u(fp8), v(bf16); x read fp32 once -----
  int gb = bid - HIST_BLOCKS;
  int w = threadIdx.x >> 6, l = threadIdx.x & 63;
  int r2 = l & 15, q = l >> 4;
  int sw = r2 & 7;
  int rowbase = gb * 64 + w * 16;
  int ra = rowbase + r2;  if (ra >= N_NODES) ra = N_NODES - 1;
  bf16x8 A[4];
#pragma unroll
  for (int k = 0; k < 4; k++)
    A[k] = pack8(x + ra * F + q * 8 + 32 * k);

  // ---- phase 1: stage wt; xt = x@W + b -> uxt[.][128:384) bf16 ----
  for (int c = threadIdx.x; c < 128 * 16; c += 256) {
    int row = c >> 4, slot = c & 15;
    *(bf16x8*)&wl[row * 128 + ((slot ^ (row & 7)) << 3)] =
        *(const bf16x8*)(wt + row * 128 + slot * 8);
  }
  __syncthreads();
#pragma unroll 1
  for (int h = 0; h < 2; h++) {
    float bv[4];
#pragma unroll
    for (int nf = 0; nf < 4; nf++) bv[nf] = bias[r2 + 16 * (4 * h + nf)];
    f32x4 acc[4] = {};
#pragma unroll
    for (int k = 0; k < 4; k++) {
#pragma unroll
      for (int nf = 0; nf < 4; nf++) {
        int nfa = 4 * h + nf;
        bf16x8 b = *(const bf16x8*)&wl[(16 * nfa + r2) * 128 + (((q + 4 * k) ^ sw) << 3)];
        acc[nf] = __builtin_amdgcn_mfma_f32_16x16x32_bf16(A[k], b, acc[nf], 0, 0, 0);
      }
    }
#pragma unroll
    for (int nf = 0; nf < 4; nf++) {
#pragma unroll
      for (int r = 0; r < 4; r++) {
        int row = rowbase + 4 * q + r;
        int c = r2 + 16 * (4 * h + nf);
        if (row < N_NODES)
          *(u16*)(uxt + (size_t)row * ROWB + 128 + 2 * c) = f2bf(acc[nf][r] + bv[nf]);
      }
    }
  }
  __syncthreads();
  // ---- phase 2: stage W1s; u = x@W1s -> uxt[.][0:128) fp8 ----
  for (int c = threadIdx.x; c < 128 * 16; c += 256) {
    int row = c >> 4, slot = c & 15;
    *(bf16x8*)&wl[row * 128 + ((slot ^ (row & 7)) << 3)] =
        *(const bf16x8*)(w1t2 + row * 128 + slot * 8);
  }
  __syncthreads();
#pragma unroll 1
  for (int h = 0; h < 2; h++) {
    f32x4 acc[4] = {};
#pragma unroll
    for (int k = 0; k < 4; k++) {
#pragma unroll
      for (int nf = 0; nf < 4; nf++) {
        int nfa = 4 * h + nf;
        bf16x8 b = *(const bf16x8*)&wl[(16 * nfa + r2) * 128 + (((q + 4 * k) ^ sw) << 3)];
        acc[nf] = __builtin_amdgcn_mfma_f32_16x16x32_bf16(A[k], b, acc[nf], 0, 0, 0);
      }
    }
#pragma unroll
    for (int nf = 0; nf < 4; nf++) {
#pragma unroll
      for (int r = 0; r < 4; r++) {
        int row = rowbase + 4 * q + r;
        int c = r2 + 16 * (4 * h + nf);
        if (row < N_NODES)
          uxt[(size_t)row * ROWB + c] = (unsigned char)f32_to_fp8(acc[nf][r]);
      }
    }
  }
  __syncthreads();
  // ---- phase 3: stage W1d; v = x@W1d + b1 -> vout bf16 ----
  for (int c = threadIdx.x; c < 128 * 16; c += 256) {
    int row = c >> 4, slot = c & 15;
    *(bf16x8*)&wl[row * 128 + ((slot ^ (row & 7)) << 3)] =
        *(const bf16x8*)(w1t2 + 128 * 128 + row * 128 + slot * 8);
  }
  __syncthreads();
#pragma unroll 1
  for (int h = 0; h < 2; h++) {
    float b1v[4];
#pragma unroll
    for (int nf = 0; nf < 4; nf++) b1v[nf] = b1[r2 + 16 * (4 * h + nf)];
    f32x4 acc[4] = {};
#pragma unroll
    for (int k = 0; k < 4; k++) {
#pragma unroll
      for (int nf = 0; nf < 4; nf++) {
        int nfa = 4 * h + nf;
        bf16x8 b = *(const bf16x8*)&wl[(16 * nfa + r2) * 128 + (((q + 4 * k) ^ sw) << 3)];
        acc[nf] = __builtin_amdgcn_mfma_f32_16x16x32_bf16(A[k], b, acc[nf], 0, 0, 0);
      }
    }
#pragma unroll
    for (int nf = 0; nf < 4; nf++) {
#pragma unroll
      for (int r = 0; r < 4; r++) {
        int row = rowbase + 4 * q + r;
        int c = r2 + 16 * (4 * h + nf);
        if (row < N_NODES) vout[row * F + c] = f2bf(acc[nf][r] + b1v[nf]);
      }
    }
  }
}

// ---------- hierarchical scan: 49-block partial scan ----------
#define SCAN_BLOCKS 49
__global__ __launch_bounds__(1024) void scan1_kernel(const int* __restrict__ deg,
                                                     int* __restrict__ offsets,
                                                     int* __restrict__ bsum) {
  __shared__ int wsum[16];
  int t = threadIdx.x, lane = t & 63, wid = t >> 6;
  int i = blockIdx.x * 1024 + t;
  int v = (i < N_NODES) ? deg[i] : 0;
  int s = v;
#pragma unroll
  for (int d = 1; d < 64; d <<= 1) {
    int u = __shfl_up(s, d);
    if (lane >= d) s += u;
  }
  if (lane == 63) wsum[wid] = s;
  __syncthreads();
  if (wid == 0 && lane < 16) {
    int ws = wsum[lane];
#pragma unroll
    for (int d = 1; d < 16; d <<= 1) {
      int u = __shfl_up(ws, d);
      if (lane >= d) ws += u;
    }
    wsum[lane] = ws;
  }
  __syncthreads();
  int wprev = (wid == 0) ? 0 : wsum[wid - 1];
  if (i < N_NODES) offsets[i] = wprev + s - v;  // block-local exclusive
  if (t == 0) bsum[blockIdx.x] = wsum[15];
}

// ---------- scan of block sums (redundant per block) + add base ----------
__global__ __launch_bounds__(256) void scan23_kernel(int* __restrict__ offsets,
                                                     const int* __restrict__ bsum) {
  __shared__ int base[SCAN_BLOCKS + 1];
  if (threadIdx.x < 64) {
    int t = threadIdx.x;
    int v = (t < SCAN_BLOCKS) ? bsum[t] : 0;
    int s = v;
#pragma unroll
    for (int d = 1; d < 64; d <<= 1) {
      int u = __shfl_up(s, d);
      if (t >= d) s += u;
    }
    if (t < SCAN_BLOCKS) base[t] = s - v;
    if (t == SCAN_BLOCKS - 1) base[SCAN_BLOCKS] = s;
  }
  __syncthreads();
  int i = blockIdx.x * blockDim.x + threadIdx.x;
  if (i < N_NODES) offsets[i] += base[i >> 10];
  if (i == 0) offsets[N_NODES] = base[SCAN_BLOCKS];
}

// ---------- reorder: atomic-free scatter, srcs16[offsets[d]+loc[e]] = src ----------
__global__ void reorder_kernel(const int* __restrict__ ei, const int* __restrict__ offsets,
                               const int* __restrict__ loc, u16* __restrict__ srcs16) {
  int e = blockIdx.x * blockDim.x + threadIdx.x;
  if (e < N_EDGES) {
    int s = clampi(ei[e]);
    int d = clampi(ei[N_EDGES + e]);
    srcs16[offsets[d] + loc[e]] = (u16)s;
  }
}

// ---------- fused gate + aggregate: one wave per dst node ----------
__global__ __launch_bounds__(256) void edge_fused_kernel(
    const unsigned char* __restrict__ uxt, const u16* __restrict__ v,
    const int* __restrict__ offsets, const u16* __restrict__ srcs16,
    const float* __restrict__ w2f, const float* __restrict__ b2,
    float* __restrict__ out)
{
  int n = (blockIdx.x * blockDim.x + threadIdx.x) >> 6;
  if (n >= N_NODES) return;
  int lane = threadIdx.x & 63;
  int g = lane >> 4, j = lane & 15;
  float w2v[8], vn[8];
  float4 wa = *(const float4*)(w2f + 8 * j);
  float4 wb = *(const float4*)(w2f + 8 * j + 4);
  w2v[0] = wa.x; w2v[1] = wa.y; w2v[2] = wa.z; w2v[3] = wa.w;
  w2v[4] = wb.x; w2v[5] = wb.y; w2v[6] = wb.z; w2v[7] = wb.w;
  bf16x8 vv = *(const bf16x8*)(v + n * F + 8 * j);
#pragma unroll
  for (int i = 0; i < 8; i++) vn[i] = (float)vv[i];
  float bias2 = b2[0];
  float acc[8] = {};
  int p = offsets[n], end = offsets[n + 1];
  for (int base = p; base < end; base += 4) {
    int slot = base + g;
    bool valid = slot < end;
    int sp = srcs16[valid ? slot : end - 1];
    const unsigned char* row = uxt + (size_t)sp * ROWB;
    uint2 up = *(const uint2*)(row + 8 * j);            // 8 fp8 u values
    bf16x8 xx = *(const bf16x8*)(row + 128 + 16 * j);   // 8 bf16 xt values
    f32x2 u01 = fp8x2_to_f32(up.x & 0xffffu);
    f32x2 u23 = fp8x2_to_f32(up.x >> 16);
    f32x2 u45 = fp8x2_to_f32(up.y & 0xffffu);
    f32x2 u67 = fp8x2_to_f32(up.y >> 16);
    float uu[8] = {u01[0], u01[1], u23[0], u23[1], u45[0], u45[1], u67[0], u67[1]};
    float t = 0.f;
#pragma unroll
    for (int i = 0; i < 8; i++) {
      float h = uu[i] + vn[i];
      h = h > 0.f ? h : 0.f;
      t += h * w2v[i];
    }
    t += __shfl_xor(t, 1);
    t += __shfl_xor(t, 2);
    t += __shfl_xor(t, 4);
    t += __shfl_xor(t, 8);
    float gate = valid ? 1.0f / (1.0f + __expf(-(t + bias2))) : 0.f;
#pragma unroll
    for (int i = 0; i < 8; i++) acc[i] += gate * (float)xx[i];
  }
#pragma unroll
  for (int i = 0; i < 8; i++) acc[i] += __shfl_xor(acc[i], 16);
#pragma unroll
  for (int i = 0; i < 8; i++) acc[i] += __shfl_xor(acc[i], 32);
  if (g == 0) {
    float4 o0, o1;
    o0.x = acc[0]; o0.y = acc[1]; o0.z = acc[2]; o0.w = acc[3];
    o1.x = acc[4]; o1.y = acc[5]; o1.z = acc[6]; o1.w = acc[7];
    *(float4*)(out + n * F + 8 * j) = o0;
    *(float4*)(out + n * F + 8 * j + 4) = o1;
  }
}

extern "C" void kernel_launch(void* const* d_in, const int* in_sizes, int n_in,
                              void* d_out, int out_size, void* d_ws, size_t ws_size,
                              hipStream_t stream) {
  const float* x  = (const float*)d_in[0];
  const int* ei   = (const int*)d_in[1];   // int64 in reference -> int32 in harness
  const float* W  = (const float*)d_in[2];
  const float* b  = (const float*)d_in[3];
  const float* W1 = (const float*)d_in[4];
  const float* b1 = (const float*)d_in[5];
  const float* W2 = (const float*)d_in[6];
  const float* b2 = (const float*)d_in[7];
  float* out = (float*)d_out;

  char* ws = (char*)d_ws;
  unsigned char* uxt = (unsigned char*)ws;    // 19,200,000 B  [n]: u fp8 | xt bf16
  u16* vout    = (u16*)(ws + 19200000);       // 12,800,000 B
  u16* wt      = (u16*)(ws + 32000000);       //     32,768 B
  u16* w1t2    = (u16*)(ws + 32032768);       //     65,536 B
  int* offsets = (int*)(ws + 32098304);       //    200,004 B
  int* deg     = (int*)(ws + 32298308);       //    200,000 B
  int* loc     = (int*)(ws + 32498308);       //  3,200,000 B
  u16* srcs16  = (u16*)(ws + 35698308);       //  1,600,000 B
  int* bsum    = (int*)(ws + 37298308);       //        196 B   total ~37.3 MB
  (void)ws_size;

  pre_kernel<<<ZERO_BLOCKS + PREP_BLOCKS, 256, 0, stream>>>(deg, W, W1, wt, w1t2);
  heavy_kernel<<<HIST_BLOCKS + GEMM_BLOCKS, 256, 0, stream>>>(
      ei, deg, loc, x, wt, w1t2, b, b1, uxt, vout);
  scan1_kernel<<<SCAN_BLOCKS, 1024, 0, stream>>>(deg, offsets, bsum);
  scan23_kernel<<<(N_NODES + 255) / 256, 256, 0, stream>>>(offsets, bsum);
  reorder_kernel<<<(N_EDGES + 255) / 256, 256, 0, stream>>>(ei, offsets, loc, srcs16);
  edge_fused_kernel<<<(N_NODES * 64 + 255) / 256, 256, 0, stream>>>(
      uxt, vout, offsets, srcs16, W2, b2, out);
}